// Round 14
// baseline (339.975 us; speedup 1.0000x reference)
//
#include <hip/hip_runtime.h>

#define NB 64
#define NN 512
#define NL 12
#define ND 128
#define NZ 384
#define NCONV 3
#define VOCAB 1000
#define BN_EPS 1e-3f
#define LO_SCALE 2048.0f
#define INV_LO (1.0f/2048.0f)
#define SCF (-1.4426950408889634f)   // -log2(e): f-part scale
#define SCS ( 2.8853900817779268f)   //  2*log2(e): s-part scale

typedef _Float16 f16;
using half8 = __attribute__((ext_vector_type(8))) _Float16;
using floatx16 = __attribute__((ext_vector_type(16))) float;

__device__ __forceinline__ floatx16 mfma32(half8 a, half8 b, floatx16 c) {
    return __builtin_amdgcn_mfma_f32_32x32x16_f16(a, b, c, 0, 0, 0);
}
__device__ __forceinline__ void split1(float x, f16& h, f16& l) {
    h = (f16)x; l = (f16)((x - (float)h) * LO_SCALE);
}
// async global->LDS: per-lane global src, wave-uniform LDS base; lane i's 16B
// lands at ldsbase + i*16. Drained by the vmcnt(0) the compiler emits at the barrier.
__device__ __forceinline__ void gl_lds16(const void* g, void* l) {
    __builtin_amdgcn_global_load_lds(
        (const __attribute__((address_space(1))) void*)g,
        (__attribute__((address_space(3))) void*)l, 16, 0, 0);
}

// ---- merged setup ----
// blocks [0,768): weight prep | [768,864): EW table (f32) | [864,866): BN pack | [866,17250): embed
__global__ __launch_bounds__(256) void setup_kernel(
    const float* __restrict__ wf, const float* __restrict__ wsg,
    f16* __restrict__ Wc_hi, f16* __restrict__ Wc_lo,
    const float* __restrict__ edge_w, float* __restrict__ EWp,
    const float* __restrict__ bn_gamma, const float* __restrict__ bn_beta,
    const float* __restrict__ bn_mean, const float* __restrict__ bn_var,
    float* __restrict__ bnp,
    const int* __restrict__ node_types, const float* __restrict__ slot_types,
    const float* __restrict__ node_w, float* __restrict__ vA)
{
    __shared__ float se[32][128];
    const int blk = blockIdx.x;
    const int tid = threadIdx.x;
    if (blk < 768) {
        int id = blk * 256 + tid;                  // 196608
        int c = id >> 16;
        int rem = id & 65535;
        int col = rem >> 7, k = rem & 127;
        int part = col >> 7;
        int d = col & 127;
        int z = (part < 2) ? (128 + k) : k;
        const float* W = (part & 1) ? wsg : wf;
        float wv = W[((size_t)c * NZ + z) * ND + d];
        f16 h, l; split1(wv, h, l);
        size_t dst = (size_t)c * 65536 + (size_t)(k >> 3) * 4096 + col * 8 + (k & 7);
        Wc_hi[dst] = h; Wc_lo[dst] = l;
    } else if (blk < 864) {
        const int bid = blk - 768;
        const int c = bid >> 5;
        const int tyg = (bid & 31) * 32;
        for (int i = tid; i < 4096; i += 256) {
            int ty = i >> 7, k = i & 127;
            int tyv = tyg + ty;
            se[ty][k] = (tyv < VOCAB) ? edge_w[(size_t)tyv * ND + k] : 0.f;
        }
        __syncthreads();
        const int h = tid >> 7, col = tid & 127;
        const float* W = h ? wsg : wf;
        const float sc = h ? SCS : SCF;
        float acc[32];
        #pragma unroll
        for (int ty = 0; ty < 32; ++ty) acc[ty] = 0.f;
        #pragma unroll 4
        for (int k = 0; k < 128; ++k) {
            float wv = W[((size_t)c * NZ + 256 + k) * ND + col];
            #pragma unroll
            for (int ty = 0; ty < 32; ++ty) acc[ty] = fmaf(se[ty][k], wv, acc[ty]);
        }
        #pragma unroll
        for (int ty = 0; ty < 32; ++ty) {
            int tyv = tyg + ty;
            if (tyv <= VOCAB)   // zero pad row at index VOCAB
                EWp[((size_t)c * (VOCAB + 1) + tyv) * 256 + (col & 63) * 4 + (col >> 6) * 2 + h] = acc[ty] * sc;
        }
    } else if (blk < 866) {
        int t = (blk - 864) * 256 + tid;           // [0,512)
        if (t < NCONV * ND) {
            int c = t >> 7, j = t & 127;
            float4 q;
            q.x = bn_gamma[c * ND + j];
            q.y = bn_beta[c * ND + j];
            q.z = bn_mean[c * ND + j];
            q.w = 1.f / sqrtf(bn_var[c * ND + j] + BN_EPS);
            *(float4*)(bnp + (size_t)t * 4) = q;
        }
    } else {
        int i = (blk - 866) * 256 + tid;
        int bn = i >> 7, d = i & 127;
        int ty = node_types[bn];
        float m = ty >= 0 ? 1.f : 0.f;
        int idx = ty >= 0 ? ty : 0;
        vA[i] = node_w[(size_t)idx * ND + d] * m + slot_types[i];
    }
}

// ---- PS-GEMM -> Ppk/Spk float4-paired layout [node][ds]{f,s,f+64,s+64}; depth-2 B prefetch ----
__global__ __launch_bounds__(256, 3) void psgemm_kernel(
    const float* __restrict__ vA,
    const f16* __restrict__ Wc_hi, const f16* __restrict__ Wc_lo,  // pre-offset by conv
    const float* __restrict__ bfv, const float* __restrict__ bsv,  // pre-offset by conv
    float* __restrict__ Ppk, float* __restrict__ Spk)
{
    __shared__ __align__(16) char sA[16384];   // hi 32x256B @0, lo @8192 (XOR-swizzled)
    const int hw = blockIdx.x;
    const int xcd = hw & 7;
    const int q = hw >> 3;            // [0,256): 8 local batches x 2 halves x 16 groups
    const int bl = q >> 5;
    const int r = q & 31;
    const int half = r >> 4;
    const int xloc = r & 15;
    const int batch = bl * 8 + xcd;
    const int node0 = batch * NN + xloc * 32;

    const int tid = threadIdx.x;
    const int lane = tid & 63, w = tid >> 6;
    const int l31 = lane & 31, l32 = lane >> 5;

    #pragma unroll
    for (int it = 0; it < 2; ++it) {
        int slot = it * 256 + tid;
        int rr = slot >> 4, cc = slot & 15;
        int cs = cc ^ (rr & 15);
        const float* vp = vA + (size_t)(node0 + rr) * ND + cs * 8;
        float4 u0 = *(const float4*)vp;
        float4 u1 = *(const float4*)(vp + 4);
        float uu[8] = {u0.x, u0.y, u0.z, u0.w, u1.x, u1.y, u1.z, u1.w};
        half8 hh, ll;
        #pragma unroll
        for (int jj = 0; jj < 8; ++jj) {
            f16 h, l; split1(uu[jj], h, l);
            hh[jj] = h; ll[jj] = l;
        }
        *(half8*)(sA + rr * 256 + cc * 16) = hh;
        *(half8*)(sA + 8192 + rr * 256 + cc * 16) = ll;
    }
    __syncthreads();

    const int dcol = w * 32 + l31;
    const int col0 = half * 256 + dcol;     // f-part column
    const int col1 = col0 + 128;            // s-part column

    floatx16 a00 = {}, a10 = {}, a01 = {}, a11 = {};

    half8 B[3][4];
    #define LDB(dst, ks) { \
        size_t k0 = (size_t)((ks) * 2 + l32) * 4096; \
        (dst)[0] = *(const half8*)(Wc_hi + k0 + col0 * 8); \
        (dst)[1] = *(const half8*)(Wc_lo + k0 + col0 * 8); \
        (dst)[2] = *(const half8*)(Wc_hi + k0 + col1 * 8); \
        (dst)[3] = *(const half8*)(Wc_lo + k0 + col1 * 8); }
    LDB(B[0], 0)
    LDB(B[1], 1)

    #pragma unroll
    for (int ks = 0; ks < 8; ++ks) {
        if (ks < 6) LDB(B[(ks + 2) % 3], ks + 2)
        const half8* Bc = B[ks % 3];
        int qq = (((ks * 2 + l32) ^ (l31 & 15)) << 4);
        half8 ah = *(const half8*)(sA + l31 * 256 + qq);
        half8 al = *(const half8*)(sA + 8192 + l31 * 256 + qq);
        a00 = mfma32(ah, Bc[0], a00);
        a10 = mfma32(ah, Bc[1], a10);
        a10 = mfma32(al, Bc[0], a10);
        a01 = mfma32(ah, Bc[2], a01);
        a11 = mfma32(ah, Bc[3], a11);
        a11 = mfma32(al, Bc[2], a11);
    }
    #undef LDB

    float bx = 0.f, by = 0.f;
    if (half) { bx = bfv[dcol]; by = bsv[dcol]; }
    float* outp = half ? Spk : Ppk;
    const int dsub = (dcol & 63) * 4 + (dcol >> 6) * 2;
    #pragma unroll
    for (int rr = 0; rr < 16; ++rr) {
        int orow = (rr & 3) + 8 * (rr >> 2) + 4 * l32;
        float2 v2 = { (a00[rr] + a10[rr] * INV_LO + bx) * SCF,
                      (a01[rr] + a11[rr] * INV_LO + by) * SCS };
        *(float2*)(outp + (size_t)(node0 + orow) * 256 + dsub) = v2;
    }
}

// ---- edge epilogue: rows DMA'd L2->LDS via global_load_lds (bypass L1/VGPR) ----
// Block = 2 nodes, 4 waves. Per-node slab (25600B): S @0 | P[l] @1024+l*1024 | EW[e] @13312+e*1024.
// Wave (node, part): part0 DMAs S + P0..8 + EW9..11 (13 rows); part1 DMAs P9..11 + EW0..8 (12 rows).
__global__ __launch_bounds__(256, 3) void edge_epilogue_kernel(
    float* __restrict__ vA,
    const int* __restrict__ neighbor_list, const int* __restrict__ edge_types,
    const float* __restrict__ Ppk, const float* __restrict__ Spk,
    const float* __restrict__ EWp, const float* __restrict__ bnp)
{
    __shared__ __align__(16) char sL[2][25600];
    __shared__ float s_red[2][64][2];
    const int hw = blockIdx.x;               // [0,16384)
    const int xcd = hw & 7;
    const int q = hw >> 3;                   // [0,2048): 8 local batches x 256 pairs
    const int b = (q >> 8) * 8 + xcd;
    const int j = q & 255;
    const int node0 = b * NN + j * 2;

    const int tid = threadIdx.x;
    const int w = tid >> 6, lane = tid & 63;
    const int nl_ = w >> 1;                  // node within pair
    const int part = w & 1;
    const int node = node0 + nl_;
    const int bbase = b * NN;

    // lanes 0..11 hold this node's 12 neighbor/edge indices
    int nlv = -1, etv = -1;
    if (lane < NL) {
        nlv = neighbor_list[node * NL + lane];
        etv = edge_types[node * NL + lane];
    }
    unsigned long long bm = __ballot(nlv >= 0);   // bits 0..11

    char* nb = sL[nl_];
    if (!part) {
        gl_lds16(Spk + (size_t)node * 256 + lane * 4, nb);
        #pragma unroll
        for (int l = 0; l < 9; ++l) {
            int nlx = __builtin_amdgcn_readlane(nlv, l);
            int ns = (nlx >= 0) ? (bbase + nlx) : node;     // safe row
            gl_lds16(Ppk + (size_t)ns * 256 + lane * 4, nb + 1024 + l * 1024);
        }
        #pragma unroll
        for (int e = 9; e < 12; ++e) {
            int et = __builtin_amdgcn_readlane(etv, e);
            int es = (et >= 0) ? et : VOCAB;                // zero pad row
            gl_lds16(EWp + (size_t)es * 256 + lane * 4, nb + 13312 + e * 1024);
        }
    } else {
        #pragma unroll
        for (int l = 9; l < 12; ++l) {
            int nlx = __builtin_amdgcn_readlane(nlv, l);
            int ns = (nlx >= 0) ? (bbase + nlx) : node;
            gl_lds16(Ppk + (size_t)ns * 256 + lane * 4, nb + 1024 + l * 1024);
        }
        #pragma unroll
        for (int e = 0; e < 9; ++e) {
            int et = __builtin_amdgcn_readlane(etv, e);
            int es = (et >= 0) ? et : VOCAB;
            gl_lds16(EWp + (size_t)es * 256 + lane * 4, nb + 13312 + e * 1024);
        }
    }
    __syncthreads();   // compiler drains vmcnt(0) before the barrier

    const int ds = lane;
    float4 sp4 = *(const float4*)(nb + ds * 16);
    float sum0 = 0.f, sum1 = 0.f;
    #pragma unroll
    for (int l = 0; l < 6; ++l) {
        int e = part * 6 + l;
        float m = ((bm >> e) & 1) ? 1.f : 0.f;              // wave-uniform
        float4 p4 = *(const float4*)(nb + 1024 + e * 1024 + ds * 16);
        float4 e4 = *(const float4*)(nb + 13312 + e * 1024 + ds * 16);
        float ax = p4.x + sp4.x + e4.x;                     // pf ch0 (* -log2e)
        float ay = p4.y + sp4.y + e4.y;                     // ps ch0 (* 2log2e)
        float az = p4.z + sp4.z + e4.z;                     // pf ch1
        float aw = p4.w + sp4.w + e4.w;                     // ps ch1
        float u0 = __builtin_amdgcn_exp2f(fminf(ax, 60.f));
        float w0 = __builtin_amdgcn_exp2f(fminf(ay, 60.f));
        float u1 = __builtin_amdgcn_exp2f(fminf(az, 60.f));
        float w1 = __builtin_amdgcn_exp2f(fminf(aw, 60.f));
        float r0 = __builtin_amdgcn_rcpf(fmaf(u0, w0, 1.f + u0 + w0));
        float r1 = __builtin_amdgcn_rcpf(fmaf(u1, w1, 1.f + u1 + w1));
        sum0 = fmaf((w0 - 1.f) * r0, m, sum0);
        sum1 = fmaf((w1 - 1.f) * r1, m, sum1);
    }

    if (part) { s_red[nl_][ds][0] = sum0; s_red[nl_][ds][1] = sum1; }
    __syncthreads();
    if (!part) {
        sum0 += s_red[nl_][ds][0];
        sum1 += s_red[nl_][ds][1];
        size_t i0 = (size_t)node * ND + ds;
        size_t i1 = i0 + 64;
        float x0 = vA[i0] + sum0;
        float x1 = vA[i1] + sum1;
        int valid = __all(fabsf(x0) > 1e-5f && fabsf(x1) > 1e-5f);  // 128 ch in-wave
        float4 q0 = *(const float4*)(bnp + (size_t)ds * 4);
        float4 q1 = *(const float4*)(bnp + (size_t)(ds + 64) * 4);
        vA[i0] = valid ? (q0.x * (x0 - q0.z) * q0.w + q0.y) : 0.f;
        vA[i1] = valid ? (q1.x * (x1 - q1.z) * q1.w + q1.y) : 0.f;
    }
}

// ---- pool: one kernel; 64 blocks x 512 threads ----
__global__ __launch_bounds__(512) void pool_kernel(
    const float* __restrict__ vA, const int* __restrict__ node_types,
    const float* __restrict__ dense_w, const float* __restrict__ dense_b,
    float* __restrict__ out)
{
    __shared__ float s_sum[4][128];
    __shared__ float s_cnt[4];
    __shared__ float s_part[2];
    const int b = blockIdx.x;
    const int tid = threadIdx.x;
    const int d = tid & 127, chunk = tid >> 7;
    const int nbase = b * NN + chunk * 128;
    float sum = 0.f, cnt = 0.f;
    #pragma unroll 4
    for (int i = 0; i < 128; ++i) {
        int ty = node_types[nbase + i];
        float mk = ty >= 0 ? 1.f : 0.f;
        sum += vA[(size_t)(nbase + i) * ND + d] * mk;
        cnt += mk;
    }
    s_sum[chunk][d] = sum;
    if (d == 0) s_cnt[chunk] = cnt;
    __syncthreads();
    if (chunk == 0) {
        float tot = s_sum[0][d] + s_sum[1][d] + s_sum[2][d] + s_sum[3][d];
        float tcnt = s_cnt[0] + s_cnt[1] + s_cnt[2] + s_cnt[3];
        float pv = (tot / tcnt) * dense_w[d];
        #pragma unroll
        for (int off = 32; off > 0; off >>= 1) pv += __shfl_down(pv, off);
        if ((d & 63) == 0) s_part[d >> 6] = pv;
    }
    __syncthreads();
    if (tid == 0) out[b] = s_part[0] + s_part[1] + dense_b[0];
}

extern "C" void kernel_launch(void* const* d_in, const int* in_sizes, int n_in,
                              void* d_out, int out_size, void* d_ws, size_t ws_size,
                              hipStream_t stream) {
    const int*   node_types    = (const int*)d_in[0];
    const int*   neighbor_list = (const int*)d_in[1];
    const int*   edge_types    = (const int*)d_in[2];
    const float* slot_types    = (const float*)d_in[3];
    const float* node_w        = (const float*)d_in[4];
    const float* edge_w        = (const float*)d_in[5];
    const float* wf            = (const float*)d_in[6];
    const float* bfv           = (const float*)d_in[7];
    const float* wsg           = (const float*)d_in[8];
    const float* bsv           = (const float*)d_in[9];
    const float* bn_gamma      = (const float*)d_in[10];
    const float* bn_beta       = (const float*)d_in[11];
    const float* bn_mean       = (const float*)d_in[12];
    const float* bn_var        = (const float*)d_in[13];
    const float* dense_w       = (const float*)d_in[14];
    const float* dense_b       = (const float*)d_in[15];
    float* out = (float*)d_out;

    float* wsf = (float*)d_ws;
    float* Ppk = wsf;                              // 8,388,608 f32
    float* Spk = wsf + 8388608;                    // 8,388,608 f32
    float* EWp = wsf + 2 * 8388608;                // 3*1001*256 = 768,768 f32
    float* bnp = EWp + 768768;                     // 1,536 f32
    float* vA  = bnp + 1536;                       // 4,194,304 f32
    f16* Wc_hi = (f16*)(vA + 4194304);             // 196,608 f16
    f16* Wc_lo = Wc_hi + 196608;                   // 196,608 f16

    setup_kernel<<<17250, 256, 0, stream>>>(
        wf, wsg, Wc_hi, Wc_lo, edge_w, EWp,
        bn_gamma, bn_beta, bn_mean, bn_var, bnp,
        node_types, slot_types, node_w, vA);

    for (int c = 0; c < NCONV; ++c) {
        psgemm_kernel<<<2048, 256, 0, stream>>>(
            vA, Wc_hi + (size_t)c * 65536, Wc_lo + (size_t)c * 65536,
            bfv + c * ND, bsv + c * ND, Ppk, Spk);
        edge_epilogue_kernel<<<16384, 256, 0, stream>>>(
            vA, neighbor_list, edge_types,
            Ppk, Spk, EWp + (size_t)c * (VOCAB + 1) * 256,
            bnp + (size_t)c * 512);
    }

    pool_kernel<<<NB, 512, 0, stream>>>(vA, node_types, dense_w, dense_b, out);
}

// Round 15
// 337.603 us; speedup vs baseline: 1.0070x; 1.0070x over previous
//
#include <hip/hip_runtime.h>

#define NB 64
#define NN 512
#define NL 12
#define ND 128
#define NZ 384
#define NCONV 3
#define VOCAB 1000
#define BN_EPS 1e-3f
#define LO_SCALE 2048.0f
#define INV_LO (1.0f/2048.0f)
#define SCF (-1.4426950408889634f)   // -log2(e): f-part scale
#define SCS ( 2.8853900817779268f)   //  2*log2(e): s-part scale

typedef _Float16 f16;
using half8 = __attribute__((ext_vector_type(8))) _Float16;
using floatx16 = __attribute__((ext_vector_type(16))) float;

__device__ __forceinline__ floatx16 mfma32(half8 a, half8 b, floatx16 c) {
    return __builtin_amdgcn_mfma_f32_32x32x16_f16(a, b, c, 0, 0, 0);
}
__device__ __forceinline__ void split1(float x, f16& h, f16& l) {
    h = (f16)x; l = (f16)((x - (float)h) * LO_SCALE);
}

// ---- merged setup ----
// blocks [0,768): weight prep | [768,864): EW table | [864,866): BN pack | [866,17250): embed
__global__ __launch_bounds__(256) void setup_kernel(
    const float* __restrict__ wf, const float* __restrict__ wsg,
    f16* __restrict__ Wc_hi, f16* __restrict__ Wc_lo,
    const float* __restrict__ edge_w, float* __restrict__ EWp,
    const float* __restrict__ bn_gamma, const float* __restrict__ bn_beta,
    const float* __restrict__ bn_mean, const float* __restrict__ bn_var,
    float* __restrict__ bnp,
    const int* __restrict__ node_types, const float* __restrict__ slot_types,
    const float* __restrict__ node_w, float* __restrict__ vA)
{
    __shared__ float se[32][128];
    const int blk = blockIdx.x;
    const int tid = threadIdx.x;
    if (blk < 768) {
        // prep: concatenated weight, k-chunk-major, f16 hi/lo
        int id = blk * 256 + tid;                  // 196608
        int c = id >> 16;
        int rem = id & 65535;
        int col = rem >> 7, k = rem & 127;
        int part = col >> 7;
        int d = col & 127;
        int z = (part < 2) ? (128 + k) : k;
        const float* W = (part & 1) ? wsg : wf;
        float wv = W[((size_t)c * NZ + z) * ND + d];
        f16 h, l; split1(wv, h, l);
        size_t dst = (size_t)c * 65536 + (size_t)(k >> 3) * 4096 + col * 8 + (k & 7);
        Wc_hi[dst] = h; Wc_lo[dst] = l;
    } else if (blk < 864) {
        // ew: EWp[c][type][ds] = float4{f(ds)*SCF, s(ds)*SCS, f(ds+64)*SCF, s(ds+64)*SCS}
        const int bid = blk - 768;
        const int c = bid >> 5;
        const int tyg = (bid & 31) * 32;
        for (int i = tid; i < 4096; i += 256) {
            int ty = i >> 7, k = i & 127;
            int tyv = tyg + ty;
            se[ty][k] = (tyv < VOCAB) ? edge_w[(size_t)tyv * ND + k] : 0.f;
        }
        __syncthreads();
        const int h = tid >> 7, col = tid & 127;
        const float* W = h ? wsg : wf;
        const float sc = h ? SCS : SCF;
        float acc[32];
        #pragma unroll
        for (int ty = 0; ty < 32; ++ty) acc[ty] = 0.f;
        #pragma unroll 4
        for (int k = 0; k < 128; ++k) {
            float wv = W[((size_t)c * NZ + 256 + k) * ND + col];
            #pragma unroll
            for (int ty = 0; ty < 32; ++ty) acc[ty] = fmaf(se[ty][k], wv, acc[ty]);
        }
        #pragma unroll
        for (int ty = 0; ty < 32; ++ty) {
            int tyv = tyg + ty;
            if (tyv <= VOCAB)   // include zero pad row at index VOCAB
                EWp[((size_t)c * (VOCAB + 1) + tyv) * 256 + (col & 63) * 4 + (col >> 6) * 2 + h] = acc[ty] * sc;
        }
    } else if (blk < 866) {
        // bn pack: bnp[c*128+j] = float4{gamma, beta, mean, rsqrt(var+eps)}
        int t = (blk - 864) * 256 + tid;           // [0,512)
        if (t < NCONV * ND) {
            int c = t >> 7, j = t & 127;
            float4 q;
            q.x = bn_gamma[c * ND + j];
            q.y = bn_beta[c * ND + j];
            q.z = bn_mean[c * ND + j];
            q.w = 1.f / sqrtf(bn_var[c * ND + j] + BN_EPS);
            *(float4*)(bnp + (size_t)t * 4) = q;
        }
    } else {
        // embed: v = node_w[type]*m + slot (f32)
        int i = (blk - 866) * 256 + tid;
        int bn = i >> 7, d = i & 127;
        int ty = node_types[bn];
        float m = ty >= 0 ? 1.f : 0.f;
        int idx = ty >= 0 ? ty : 0;
        vA[i] = node_w[(size_t)idx * ND + d] * m + slot_types[i];
    }
}

// ---- PS-GEMM -> Ppk/Spk float4-paired layout [node][ds]{f,s,f+64,s+64} ----
// grid 1024: both column-halves per block (A staged once); depth-2 B prefetch ring.
__global__ __launch_bounds__(256, 3) void psgemm_kernel(
    const float* __restrict__ vA,
    const f16* __restrict__ Wc_hi, const f16* __restrict__ Wc_lo,  // pre-offset by conv
    const float* __restrict__ bfv, const float* __restrict__ bsv,  // pre-offset by conv
    float* __restrict__ Ppk, float* __restrict__ Spk)
{
    __shared__ __align__(16) char sA[16384];   // hi 32x256B @0, lo @8192 (XOR-swizzled)
    const int hw = blockIdx.x;        // [0,1024)
    const int xcd = hw & 7;
    const int q = hw >> 3;            // [0,128): 8 local batches x 16 groups
    const int bl = q >> 4;
    const int xloc = q & 15;
    const int batch = bl * 8 + xcd;
    const int node0 = batch * NN + xloc * 32;

    const int tid = threadIdx.x;
    const int lane = tid & 63, w = tid >> 6;
    const int l31 = lane & 31, l32 = lane >> 5;

    #pragma unroll
    for (int it = 0; it < 2; ++it) {
        int slot = it * 256 + tid;
        int rr = slot >> 4, cc = slot & 15;
        int cs = cc ^ (rr & 15);
        const float* vp = vA + (size_t)(node0 + rr) * ND + cs * 8;
        float4 u0 = *(const float4*)vp;
        float4 u1 = *(const float4*)(vp + 4);
        float uu[8] = {u0.x, u0.y, u0.z, u0.w, u1.x, u1.y, u1.z, u1.w};
        half8 hh, ll;
        #pragma unroll
        for (int jj = 0; jj < 8; ++jj) {
            f16 h, l; split1(uu[jj], h, l);
            hh[jj] = h; ll[jj] = l;
        }
        *(half8*)(sA + rr * 256 + cc * 16) = hh;
        *(half8*)(sA + 8192 + rr * 256 + cc * 16) = ll;
    }
    __syncthreads();

    const int dcol = w * 32 + l31;
    const int dsub = (dcol & 63) * 4 + (dcol >> 6) * 2;

    #pragma unroll 1
    for (int half = 0; half < 2; ++half) {
        const int col0 = half * 256 + dcol;     // f-part column
        const int col1 = col0 + 128;            // s-part column

        floatx16 a00 = {}, a10 = {}, a01 = {}, a11 = {};

        half8 B[3][4];
        #define LDB(dst, ks) { \
            size_t k0 = (size_t)((ks) * 2 + l32) * 4096; \
            (dst)[0] = *(const half8*)(Wc_hi + k0 + col0 * 8); \
            (dst)[1] = *(const half8*)(Wc_lo + k0 + col0 * 8); \
            (dst)[2] = *(const half8*)(Wc_hi + k0 + col1 * 8); \
            (dst)[3] = *(const half8*)(Wc_lo + k0 + col1 * 8); }
        LDB(B[0], 0)
        LDB(B[1], 1)

        #pragma unroll
        for (int ks = 0; ks < 8; ++ks) {
            if (ks < 6) LDB(B[(ks + 2) % 3], ks + 2)
            const half8* Bc = B[ks % 3];
            int qq = (((ks * 2 + l32) ^ (l31 & 15)) << 4);
            half8 ah = *(const half8*)(sA + l31 * 256 + qq);
            half8 al = *(const half8*)(sA + 8192 + l31 * 256 + qq);
            a00 = mfma32(ah, Bc[0], a00);
            a10 = mfma32(ah, Bc[1], a10);
            a10 = mfma32(al, Bc[0], a10);
            a01 = mfma32(ah, Bc[2], a01);
            a11 = mfma32(ah, Bc[3], a11);
            a11 = mfma32(al, Bc[2], a11);
        }
        #undef LDB

        float bx = 0.f, by = 0.f;
        if (half) { bx = bfv[dcol]; by = bsv[dcol]; }
        float* outp = half ? Spk : Ppk;
        #pragma unroll
        for (int rr = 0; rr < 16; ++rr) {
            int orow = (rr & 3) + 8 * (rr >> 2) + 4 * l32;
            float2 v2 = { (a00[rr] + a10[rr] * INV_LO + bx) * SCF,
                          (a01[rr] + a11[rr] * INV_LO + by) * SCS };
            *(float2*)(outp + (size_t)(node0 + orow) * 256 + dsub) = v2;
        }
    }
}

// ---- edge epilogue: 2 waves/node (6 l each); float4 gathers; LDS pair-reduce ----
__global__ __launch_bounds__(256, 4) void edge_epilogue_kernel(
    float* __restrict__ vA,
    const int* __restrict__ neighbor_list, const int* __restrict__ edge_types,
    const float* __restrict__ Ppk, const float* __restrict__ Spk,
    const float* __restrict__ EWp, const float* __restrict__ bnp)
{
    __shared__ float s_red[2][64][2];
    const int hw = blockIdx.x;               // [0,16384)
    const int xcd = hw & 7;
    const int q = hw >> 3;                   // [0,2048): 8 local batches x 256 pairs
    const int b = (q >> 8) * 8 + xcd;
    const int j = q & 255;
    const int node0 = b * NN + j * 2;

    const int tid = threadIdx.x;
    const int w = tid >> 6, ds = tid & 63;
    const int nl_ = w >> 1;                  // node within pair
    const int sub = w & 1;                   // l-half
    const int node = node0 + nl_;
    const int bbase = b * NN;

    int nlv = -1, etv = -1;
    if (ds < 6) {
        nlv = neighbor_list[node * NL + sub * 6 + ds];
        etv = edge_types[node * NL + sub * 6 + ds];
    }
    unsigned long long bm = __ballot(nlv >= 0);   // bits 0..5

    // issue gathers: 1 S + 6 P + 6 EW float4 (SGPR row bases)
    float4 sp4 = *(const float4*)(Spk + (size_t)node * 256 + ds * 4);
    float4 p4[6], e4[6];
    #pragma unroll
    for (int l = 0; l < 6; ++l) {
        int nl_l = __builtin_amdgcn_readlane(nlv, l);
        int et_l = __builtin_amdgcn_readlane(etv, l);
        int ns = (nl_l >= 0) ? (bbase + nl_l) : node;   // safe row
        int es = (et_l >= 0) ? et_l : VOCAB;            // zero pad row
        p4[l] = *(const float4*)(Ppk + (size_t)ns * 256 + ds * 4);
        e4[l] = *(const float4*)(EWp + (size_t)es * 256 + ds * 4);
    }

    float sum0 = 0.f, sum1 = 0.f;
    #pragma unroll
    for (int l = 0; l < 6; ++l) {
        float m = ((bm >> l) & 1) ? 1.f : 0.f;          // wave-uniform
        float ax = p4[l].x + sp4.x + e4[l].x;           // pf ch0 (* -log2e)
        float ay = p4[l].y + sp4.y + e4[l].y;           // ps ch0 (* 2log2e)
        float az = p4[l].z + sp4.z + e4[l].z;           // pf ch1
        float aw = p4[l].w + sp4.w + e4[l].w;           // ps ch1
        float u0 = __builtin_amdgcn_exp2f(fminf(ax, 60.f));
        float w0 = __builtin_amdgcn_exp2f(fminf(ay, 60.f));
        float u1 = __builtin_amdgcn_exp2f(fminf(az, 60.f));
        float w1 = __builtin_amdgcn_exp2f(fminf(aw, 60.f));
        float r0 = __builtin_amdgcn_rcpf(fmaf(u0, w0, 1.f + u0 + w0));
        float r1 = __builtin_amdgcn_rcpf(fmaf(u1, w1, 1.f + u1 + w1));
        sum0 = fmaf((w0 - 1.f) * r0, m, sum0);
        sum1 = fmaf((w1 - 1.f) * r1, m, sum1);
    }

    if (sub) { s_red[nl_][ds][0] = sum0; s_red[nl_][ds][1] = sum1; }
    __syncthreads();
    if (!sub) {
        sum0 += s_red[nl_][ds][0];
        sum1 += s_red[nl_][ds][1];
        size_t i0 = (size_t)node * ND + ds;
        size_t i1 = i0 + 64;
        float x0 = vA[i0] + sum0;
        float x1 = vA[i1] + sum1;
        int valid = __all(fabsf(x0) > 1e-5f && fabsf(x1) > 1e-5f);  // 128 ch in-wave
        float4 q0 = *(const float4*)(bnp + (size_t)ds * 4);
        float4 q1 = *(const float4*)(bnp + (size_t)(ds + 64) * 4);
        vA[i0] = valid ? (q0.x * (x0 - q0.z) * q0.w + q0.y) : 0.f;
        vA[i1] = valid ? (q1.x * (x1 - q1.z) * q1.w + q1.y) : 0.f;
    }
}

// ---- pool: one kernel; 64 blocks x 512 threads ----
__global__ __launch_bounds__(512) void pool_kernel(
    const float* __restrict__ vA, const int* __restrict__ node_types,
    const float* __restrict__ dense_w, const float* __restrict__ dense_b,
    float* __restrict__ out)
{
    __shared__ float s_sum[4][128];
    __shared__ float s_cnt[4];
    __shared__ float s_part[2];
    const int b = blockIdx.x;
    const int tid = threadIdx.x;
    const int d = tid & 127, chunk = tid >> 7;
    const int nbase = b * NN + chunk * 128;
    float sum = 0.f, cnt = 0.f;
    #pragma unroll 4
    for (int i = 0; i < 128; ++i) {
        int ty = node_types[nbase + i];
        float mk = ty >= 0 ? 1.f : 0.f;
        sum += vA[(size_t)(nbase + i) * ND + d] * mk;
        cnt += mk;
    }
    s_sum[chunk][d] = sum;
    if (d == 0) s_cnt[chunk] = cnt;
    __syncthreads();
    if (chunk == 0) {
        float tot = s_sum[0][d] + s_sum[1][d] + s_sum[2][d] + s_sum[3][d];
        float tcnt = s_cnt[0] + s_cnt[1] + s_cnt[2] + s_cnt[3];
        float pv = (tot / tcnt) * dense_w[d];
        #pragma unroll
        for (int off = 32; off > 0; off >>= 1) pv += __shfl_down(pv, off);
        if ((d & 63) == 0) s_part[d >> 6] = pv;
    }
    __syncthreads();
    if (tid == 0) out[b] = s_part[0] + s_part[1] + dense_b[0];
}

extern "C" void kernel_launch(void* const* d_in, const int* in_sizes, int n_in,
                              void* d_out, int out_size, void* d_ws, size_t ws_size,
                              hipStream_t stream) {
    const int*   node_types    = (const int*)d_in[0];
    const int*   neighbor_list = (const int*)d_in[1];
    const int*   edge_types    = (const int*)d_in[2];
    const float* slot_types    = (const float*)d_in[3];
    const float* node_w        = (const float*)d_in[4];
    const float* edge_w        = (const float*)d_in[5];
    const float* wf            = (const float*)d_in[6];
    const float* bfv           = (const float*)d_in[7];
    const float* wsg           = (const float*)d_in[8];
    const float* bsv           = (const float*)d_in[9];
    const float* bn_gamma      = (const float*)d_in[10];
    const float* bn_beta       = (const float*)d_in[11];
    const float* bn_mean       = (const float*)d_in[12];
    const float* bn_var        = (const float*)d_in[13];
    const float* dense_w       = (const float*)d_in[14];
    const float* dense_b       = (const float*)d_in[15];
    float* out = (float*)d_out;

    float* wsf = (float*)d_ws;
    float* Ppk = wsf;                              // 8,388,608 f32
    float* Spk = wsf + 8388608;                    // 8,388,608 f32
    float* EWp = wsf + 2 * 8388608;                // 3*1001*256 = 768,768 f32
    float* bnp = EWp + 768768;                     // 1,536 f32
    float* vA  = bnp + 1536;                       // 4,194,304 f32
    f16* Wc_hi = (f16*)(vA + 4194304);             // 196,608 f16
    f16* Wc_lo = Wc_hi + 196608;                   // 196,608 f16

    setup_kernel<<<17250, 256, 0, stream>>>(
        wf, wsg, Wc_hi, Wc_lo, edge_w, EWp,
        bn_gamma, bn_beta, bn_mean, bn_var, bnp,
        node_types, slot_types, node_w, vA);

    for (int c = 0; c < NCONV; ++c) {
        psgemm_kernel<<<1024, 256, 0, stream>>>(
            vA, Wc_hi + (size_t)c * 65536, Wc_lo + (size_t)c * 65536,
            bfv + c * ND, bsv + c * ND, Ppk, Spk);
        edge_epilogue_kernel<<<16384, 256, 0, stream>>>(
            vA, neighbor_list, edge_types,
            Ppk, Spk, EWp + (size_t)c * (VOCAB + 1) * 256,
            bnp + (size_t)c * 512);
    }

    pool_kernel<<<NB, 512, 0, stream>>>(vA, node_types, dense_w, dense_b, out);
}

// Round 16
// 246.733 us; speedup vs baseline: 1.3779x; 1.3683x over previous
//
#include <hip/hip_runtime.h>

#define NB 64
#define NN 512
#define NL 12
#define ND 128
#define NZ 384
#define NCONV 3
#define VOCAB 1000
#define BN_EPS 1e-3f
#define LO_SCALE 2048.0f
#define INV_LO (1.0f/2048.0f)
#define SCF (-1.4426950408889634f)   // -log2(e): f-part scale
#define SCS ( 2.8853900817779268f)   //  2*log2(e): s-part scale

typedef _Float16 f16;
using half8 = __attribute__((ext_vector_type(8))) _Float16;
using floatx16 = __attribute__((ext_vector_type(16))) float;

__device__ __forceinline__ floatx16 mfma32(half8 a, half8 b, floatx16 c) {
    return __builtin_amdgcn_mfma_f32_32x32x16_f16(a, b, c, 0, 0, 0);
}
__device__ __forceinline__ void split1(float x, f16& h, f16& l) {
    h = (f16)x; l = (f16)((x - (float)h) * LO_SCALE);
}

// ---- merged setup ----
// blocks [0,768): weight prep | [768,864): EW table | [864,866): BN pack | [866,17250): embed
__global__ __launch_bounds__(256) void setup_kernel(
    const float* __restrict__ wf, const float* __restrict__ wsg,
    f16* __restrict__ Wc_hi, f16* __restrict__ Wc_lo,
    const float* __restrict__ edge_w, float* __restrict__ EWp,
    const float* __restrict__ bn_gamma, const float* __restrict__ bn_beta,
    const float* __restrict__ bn_mean, const float* __restrict__ bn_var,
    float* __restrict__ bnp,
    const int* __restrict__ node_types, const float* __restrict__ slot_types,
    const float* __restrict__ node_w, float* __restrict__ vA)
{
    __shared__ float se[32][128];
    const int blk = blockIdx.x;
    const int tid = threadIdx.x;
    if (blk < 768) {
        // prep: concatenated weight, k-chunk-major, f16 hi/lo
        int id = blk * 256 + tid;                  // 196608
        int c = id >> 16;
        int rem = id & 65535;
        int col = rem >> 7, k = rem & 127;
        int part = col >> 7;
        int d = col & 127;
        int z = (part < 2) ? (128 + k) : k;
        const float* W = (part & 1) ? wsg : wf;
        float wv = W[((size_t)c * NZ + z) * ND + d];
        f16 h, l; split1(wv, h, l);
        size_t dst = (size_t)c * 65536 + (size_t)(k >> 3) * 4096 + col * 8 + (k & 7);
        Wc_hi[dst] = h; Wc_lo[dst] = l;
    } else if (blk < 864) {
        // ew: EWp[c][type][ds] = float4{f(ds)*SCF, s(ds)*SCS, f(ds+64)*SCF, s(ds+64)*SCS}
        const int bid = blk - 768;
        const int c = bid >> 5;
        const int tyg = (bid & 31) * 32;
        for (int i = tid; i < 4096; i += 256) {
            int ty = i >> 7, k = i & 127;
            int tyv = tyg + ty;
            se[ty][k] = (tyv < VOCAB) ? edge_w[(size_t)tyv * ND + k] : 0.f;
        }
        __syncthreads();
        const int h = tid >> 7, col = tid & 127;
        const float* W = h ? wsg : wf;
        const float sc = h ? SCS : SCF;
        float acc[32];
        #pragma unroll
        for (int ty = 0; ty < 32; ++ty) acc[ty] = 0.f;
        #pragma unroll 4
        for (int k = 0; k < 128; ++k) {
            float wv = W[((size_t)c * NZ + 256 + k) * ND + col];
            #pragma unroll
            for (int ty = 0; ty < 32; ++ty) acc[ty] = fmaf(se[ty][k], wv, acc[ty]);
        }
        #pragma unroll
        for (int ty = 0; ty < 32; ++ty) {
            int tyv = tyg + ty;
            if (tyv <= VOCAB)   // include zero pad row at index VOCAB
                EWp[((size_t)c * (VOCAB + 1) + tyv) * 256 + (col & 63) * 4 + (col >> 6) * 2 + h] = acc[ty] * sc;
        }
    } else if (blk < 866) {
        // bn pack: bnp[c*128+j] = float4{gamma, beta, mean, rsqrt(var+eps)}
        int t = (blk - 864) * 256 + tid;           // [0,512)
        if (t < NCONV * ND) {
            int c = t >> 7, j = t & 127;
            float4 q;
            q.x = bn_gamma[c * ND + j];
            q.y = bn_beta[c * ND + j];
            q.z = bn_mean[c * ND + j];
            q.w = 1.f / sqrtf(bn_var[c * ND + j] + BN_EPS);
            *(float4*)(bnp + (size_t)t * 4) = q;
        }
    } else {
        // embed: v = node_w[type]*m + slot (f32)
        int i = (blk - 866) * 256 + tid;
        int bn = i >> 7, d = i & 127;
        int ty = node_types[bn];
        float m = ty >= 0 ? 1.f : 0.f;
        int idx = ty >= 0 ? ty : 0;
        vA[i] = node_w[(size_t)idx * ND + d] * m + slot_types[i];
    }
}

// ---- PS-GEMM -> Ppk/Spk float4-paired layout [node][ds]{f,s,f+64,s+64}; depth-2 B prefetch ----
__global__ __launch_bounds__(256, 3) void psgemm_kernel(
    const float* __restrict__ vA,
    const f16* __restrict__ Wc_hi, const f16* __restrict__ Wc_lo,  // pre-offset by conv
    const float* __restrict__ bfv, const float* __restrict__ bsv,  // pre-offset by conv
    float* __restrict__ Ppk, float* __restrict__ Spk)
{
    __shared__ __align__(16) char sA[16384];   // hi 32x256B @0, lo @8192 (XOR-swizzled)
    const int hw = blockIdx.x;
    const int xcd = hw & 7;
    const int q = hw >> 3;            // [0,256): 8 local batches x 2 halves x 16 groups
    const int bl = q >> 5;
    const int r = q & 31;
    const int half = r >> 4;
    const int xloc = r & 15;
    const int batch = bl * 8 + xcd;
    const int node0 = batch * NN + xloc * 32;

    const int tid = threadIdx.x;
    const int lane = tid & 63, w = tid >> 6;
    const int l31 = lane & 31, l32 = lane >> 5;

    #pragma unroll
    for (int it = 0; it < 2; ++it) {
        int slot = it * 256 + tid;
        int rr = slot >> 4, cc = slot & 15;
        int cs = cc ^ (rr & 15);
        const float* vp = vA + (size_t)(node0 + rr) * ND + cs * 8;
        float4 u0 = *(const float4*)vp;
        float4 u1 = *(const float4*)(vp + 4);
        float uu[8] = {u0.x, u0.y, u0.z, u0.w, u1.x, u1.y, u1.z, u1.w};
        half8 hh, ll;
        #pragma unroll
        for (int jj = 0; jj < 8; ++jj) {
            f16 h, l; split1(uu[jj], h, l);
            hh[jj] = h; ll[jj] = l;
        }
        *(half8*)(sA + rr * 256 + cc * 16) = hh;
        *(half8*)(sA + 8192 + rr * 256 + cc * 16) = ll;
    }
    __syncthreads();

    const int dcol = w * 32 + l31;
    const int col0 = half * 256 + dcol;     // f-part column
    const int col1 = col0 + 128;            // s-part column

    floatx16 a00 = {}, a10 = {}, a01 = {}, a11 = {};

    half8 B[3][4];
    #define LDB(dst, ks) { \
        size_t k0 = (size_t)((ks) * 2 + l32) * 4096; \
        (dst)[0] = *(const half8*)(Wc_hi + k0 + col0 * 8); \
        (dst)[1] = *(const half8*)(Wc_lo + k0 + col0 * 8); \
        (dst)[2] = *(const half8*)(Wc_hi + k0 + col1 * 8); \
        (dst)[3] = *(const half8*)(Wc_lo + k0 + col1 * 8); }
    LDB(B[0], 0)
    LDB(B[1], 1)

    #pragma unroll
    for (int ks = 0; ks < 8; ++ks) {
        if (ks < 6) LDB(B[(ks + 2) % 3], ks + 2)
        const half8* Bc = B[ks % 3];
        int qq = (((ks * 2 + l32) ^ (l31 & 15)) << 4);
        half8 ah = *(const half8*)(sA + l31 * 256 + qq);
        half8 al = *(const half8*)(sA + 8192 + l31 * 256 + qq);
        a00 = mfma32(ah, Bc[0], a00);
        a10 = mfma32(ah, Bc[1], a10);
        a10 = mfma32(al, Bc[0], a10);
        a01 = mfma32(ah, Bc[2], a01);
        a11 = mfma32(ah, Bc[3], a11);
        a11 = mfma32(al, Bc[2], a11);
    }
    #undef LDB

    float bx = 0.f, by = 0.f;
    if (half) { bx = bfv[dcol]; by = bsv[dcol]; }
    float* outp = half ? Spk : Ppk;
    const int dsub = (dcol & 63) * 4 + (dcol >> 6) * 2;
    #pragma unroll
    for (int rr = 0; rr < 16; ++rr) {
        int orow = (rr & 3) + 8 * (rr >> 2) + 4 * l32;
        float2 v2 = { (a00[rr] + a10[rr] * INV_LO + bx) * SCF,
                      (a01[rr] + a11[rr] * INV_LO + by) * SCS };
        *(float2*)(outp + (size_t)(node0 + orow) * 256 + dsub) = v2;
    }
}

// ---- edge epilogue: 2 waves/node (6 l each); float4 gathers; LDS pair-reduce ----
__global__ __launch_bounds__(256, 4) void edge_epilogue_kernel(
    float* __restrict__ vA,
    const int* __restrict__ neighbor_list, const int* __restrict__ edge_types,
    const float* __restrict__ Ppk, const float* __restrict__ Spk,
    const float* __restrict__ EWp, const float* __restrict__ bnp)
{
    __shared__ float s_red[2][64][2];
    const int hw = blockIdx.x;               // [0,16384)
    const int xcd = hw & 7;
    const int q = hw >> 3;                   // [0,2048): 8 local batches x 256 pairs
    const int b = (q >> 8) * 8 + xcd;
    const int j = q & 255;
    const int node0 = b * NN + j * 2;

    const int tid = threadIdx.x;
    const int w = tid >> 6, ds = tid & 63;
    const int nl_ = w >> 1;                  // node within pair
    const int sub = w & 1;                   // l-half
    const int node = node0 + nl_;
    const int bbase = b * NN;

    int nlv = -1, etv = -1;
    if (ds < 6) {
        nlv = neighbor_list[node * NL + sub * 6 + ds];
        etv = edge_types[node * NL + sub * 6 + ds];
    }
    unsigned long long bm = __ballot(nlv >= 0);   // bits 0..5

    // issue gathers: 1 S + 6 P + 6 EW float4 (SGPR row bases)
    float4 sp4 = *(const float4*)(Spk + (size_t)node * 256 + ds * 4);
    float4 p4[6], e4[6];
    #pragma unroll
    for (int l = 0; l < 6; ++l) {
        int nl_l = __builtin_amdgcn_readlane(nlv, l);
        int et_l = __builtin_amdgcn_readlane(etv, l);
        int ns = (nl_l >= 0) ? (bbase + nl_l) : node;   // safe row
        int es = (et_l >= 0) ? et_l : VOCAB;            // zero pad row
        p4[l] = *(const float4*)(Ppk + (size_t)ns * 256 + ds * 4);
        e4[l] = *(const float4*)(EWp + (size_t)es * 256 + ds * 4);
    }
    __builtin_amdgcn_sched_barrier(0);

    float sum0 = 0.f, sum1 = 0.f;
    #pragma unroll
    for (int l = 0; l < 6; ++l) {
        float m = ((bm >> l) & 1) ? 1.f : 0.f;          // wave-uniform
        float ax = p4[l].x + sp4.x + e4[l].x;           // pf ch0 (* -log2e)
        float ay = p4[l].y + sp4.y + e4[l].y;           // ps ch0 (* 2log2e)
        float az = p4[l].z + sp4.z + e4[l].z;           // pf ch1
        float aw = p4[l].w + sp4.w + e4[l].w;           // ps ch1
        float u0 = __builtin_amdgcn_exp2f(fminf(ax, 60.f));
        float w0 = __builtin_amdgcn_exp2f(fminf(ay, 60.f));
        float u1 = __builtin_amdgcn_exp2f(fminf(az, 60.f));
        float w1 = __builtin_amdgcn_exp2f(fminf(aw, 60.f));
        float r0 = __builtin_amdgcn_rcpf(fmaf(u0, w0, 1.f + u0 + w0));
        float r1 = __builtin_amdgcn_rcpf(fmaf(u1, w1, 1.f + u1 + w1));
        sum0 = fmaf((w0 - 1.f) * r0, m, sum0);
        sum1 = fmaf((w1 - 1.f) * r1, m, sum1);
    }

    if (sub) { s_red[nl_][ds][0] = sum0; s_red[nl_][ds][1] = sum1; }
    __syncthreads();
    if (!sub) {
        sum0 += s_red[nl_][ds][0];
        sum1 += s_red[nl_][ds][1];
        size_t i0 = (size_t)node * ND + ds;
        size_t i1 = i0 + 64;
        float x0 = vA[i0] + sum0;
        float x1 = vA[i1] + sum1;
        int valid = __all(fabsf(x0) > 1e-5f && fabsf(x1) > 1e-5f);  // 128 ch in-wave
        float4 q0 = *(const float4*)(bnp + (size_t)ds * 4);
        float4 q1 = *(const float4*)(bnp + (size_t)(ds + 64) * 4);
        vA[i0] = valid ? (q0.x * (x0 - q0.z) * q0.w + q0.y) : 0.f;
        vA[i1] = valid ? (q1.x * (x1 - q1.z) * q1.w + q1.y) : 0.f;
    }
}

// ---- pool: one kernel; 64 blocks x 512 threads ----
__global__ __launch_bounds__(512) void pool_kernel(
    const float* __restrict__ vA, const int* __restrict__ node_types,
    const float* __restrict__ dense_w, const float* __restrict__ dense_b,
    float* __restrict__ out)
{
    __shared__ float s_sum[4][128];
    __shared__ float s_cnt[4];
    __shared__ float s_part[2];
    const int b = blockIdx.x;
    const int tid = threadIdx.x;
    const int d = tid & 127, chunk = tid >> 7;
    const int nbase = b * NN + chunk * 128;
    float sum = 0.f, cnt = 0.f;
    #pragma unroll 4
    for (int i = 0; i < 128; ++i) {
        int ty = node_types[nbase + i];
        float mk = ty >= 0 ? 1.f : 0.f;
        sum += vA[(size_t)(nbase + i) * ND + d] * mk;
        cnt += mk;
    }
    s_sum[chunk][d] = sum;
    if (d == 0) s_cnt[chunk] = cnt;
    __syncthreads();
    if (chunk == 0) {
        float tot = s_sum[0][d] + s_sum[1][d] + s_sum[2][d] + s_sum[3][d];
        float tcnt = s_cnt[0] + s_cnt[1] + s_cnt[2] + s_cnt[3];
        float pv = (tot / tcnt) * dense_w[d];
        #pragma unroll
        for (int off = 32; off > 0; off >>= 1) pv += __shfl_down(pv, off);
        if ((d & 63) == 0) s_part[d >> 6] = pv;
    }
    __syncthreads();
    if (tid == 0) out[b] = s_part[0] + s_part[1] + dense_b[0];
}

extern "C" void kernel_launch(void* const* d_in, const int* in_sizes, int n_in,
                              void* d_out, int out_size, void* d_ws, size_t ws_size,
                              hipStream_t stream) {
    const int*   node_types    = (const int*)d_in[0];
    const int*   neighbor_list = (const int*)d_in[1];
    const int*   edge_types    = (const int*)d_in[2];
    const float* slot_types    = (const float*)d_in[3];
    const float* node_w        = (const float*)d_in[4];
    const float* edge_w        = (const float*)d_in[5];
    const float* wf            = (const float*)d_in[6];
    const float* bfv           = (const float*)d_in[7];
    const float* wsg           = (const float*)d_in[8];
    const float* bsv           = (const float*)d_in[9];
    const float* bn_gamma      = (const float*)d_in[10];
    const float* bn_beta       = (const float*)d_in[11];
    const float* bn_mean       = (const float*)d_in[12];
    const float* bn_var        = (const float*)d_in[13];
    const float* dense_w       = (const float*)d_in[14];
    const float* dense_b       = (const float*)d_in[15];
    float* out = (float*)d_out;

    float* wsf = (float*)d_ws;
    float* Ppk = wsf;                              // 8,388,608 f32
    float* Spk = wsf + 8388608;                    // 8,388,608 f32
    float* EWp = wsf + 2 * 8388608;                // 3*1001*256 = 768,768 f32
    float* bnp = EWp + 768768;                     // 1,536 f32
    float* vA  = bnp + 1536;                       // 4,194,304 f32
    f16* Wc_hi = (f16*)(vA + 4194304);             // 196,608 f16
    f16* Wc_lo = Wc_hi + 196608;                   // 196,608 f16

    setup_kernel<<<17250, 256, 0, stream>>>(
        wf, wsg, Wc_hi, Wc_lo, edge_w, EWp,
        bn_gamma, bn_beta, bn_mean, bn_var, bnp,
        node_types, slot_types, node_w, vA);

    for (int c = 0; c < NCONV; ++c) {
        psgemm_kernel<<<2048, 256, 0, stream>>>(
            vA, Wc_hi + (size_t)c * 65536, Wc_lo + (size_t)c * 65536,
            bfv + c * ND, bsv + c * ND, Ppk, Spk);
        edge_epilogue_kernel<<<16384, 256, 0, stream>>>(
            vA, neighbor_list, edge_types,
            Ppk, Spk, EWp + (size_t)c * (VOCAB + 1) * 256,
            bnp + (size_t)c * 512);
    }

    pool_kernel<<<NB, 512, 0, stream>>>(vA, node_types, dense_w, dense_b, out);
}